// Round 13
// baseline (239.565 us; speedup 1.0000x reference)
//
#include <hip/hip_runtime.h>
#include <stdint.h>
#include <math.h>

typedef unsigned int u32;
typedef unsigned long long u64;

#define BB 8
#define AA 19206
#define CCH 91
#define NCLS 90
#define KSEL 256
#define MAXDET 100
#define NROWS (BB*NCLS)      // 720
#define NFLAT (NCLS*MAXDET)  // 9000
#define IOU_T 0.6f
#define RPW 4                // rows per wave in k_nms

// ---------------- sigmoid + transpose (per batch-chunk) ----------------
#define ATILE 64
__global__ void __launch_bounds__(256) k_sigT(const float* __restrict__ logits,
                                              float* __restrict__ sc, int b0) {
  __shared__ __align__(16) float tile[ATILE * CCH];  // 23.3 KB
  int bl = blockIdx.y;            // local batch within chunk
  int b  = b0 + bl;               // global batch
  int a0 = blockIdx.x * ATILE;
  int nt = AA - a0; if (nt > ATILE) nt = ATILE;
  int nload = nt * CCH;           // even
  const float* src = logits + ((size_t)b * AA + a0) * CCH;   // 8B aligned
  const float2* s2 = (const float2*)src;
  int n2 = nload >> 1;
  for (int i = threadIdx.x; i < n2; i += 256) ((float2*)tile)[i] = s2[i];
  __syncthreads();
  for (int j = threadIdx.x; j < ATILE * NCLS; j += 256) {
    int c  = j >> 6;       // whole wave shares c -> coalesced store
    int ai = j & 63;
    if (ai < nt) {
      float x = tile[ai * CCH + (c + 1)];
      float s = 1.0f / (1.0f + expf(-x));
      sc[((size_t)bl * NCLS + c) * AA + a0 + ai] = s;
    }
  }
}

// ---------------- per-row top-256: 2 global passes (L3-hot), small LDS ------
__global__ void __launch_bounds__(512) k_row(const float* __restrict__ sc,
    float* __restrict__ tks, int* __restrict__ tki, int row0) {
  __shared__ u32 hist[256];
  __shared__ u32 suf[256];
  __shared__ u64 cand[512];
  __shared__ int shBs, ctr;
  int rl  = blockIdx.x;
  int row = row0 + rl;
  int tid = threadIdx.x;
  const float2* src = (const float2*)(sc + (size_t)rl * AA);  // AA even
  if (tid < 256) hist[tid] = 0;
  if (tid == 0) ctr = 0;
  __syncthreads();
  for (int i = tid; i < AA / 2; i += 512) {
    float2 v = src[i];
    atomicAdd(&hist[min(255, (int)(v.x * 256.0f))], 1u);  // monotone bin
    atomicAdd(&hist[min(255, (int)(v.y * 256.0f))], 1u);
  }
  __syncthreads();
  if (tid < 256) suf[tid] = hist[tid];
  __syncthreads();
  for (int off = 1; off < 256; off <<= 1) {
    u32 v = 0;
    if (tid < 256 && tid + off < 256) v = suf[tid + off];
    __syncthreads();
    if (tid < 256) suf[tid] += v;
    __syncthreads();
  }
  if (tid < 256) {
    u32 nxt = (tid < 255) ? suf[tid + 1] : 0u;
    if (suf[tid] >= (u32)KSEL && nxt < (u32)KSEL) shBs = tid;
  }
  __syncthreads();
  int Bs = shBs;
  int lane = tid & 63;
  // pass 2: L2/L3-hot re-read, wave-aggregated LDS append of bins >= Bs
  for (int i = tid; i < AA / 2; i += 512) {
    float2 v = src[i];
    {
      bool p = min(255, (int)(v.x * 256.0f)) >= Bs;
      u64 m = __ballot(p);
      if (p) {
        int leader = (int)(__ffsll((long long)m) - 1);
        int base = 0;
        if (lane == leader) base = atomicAdd(&ctr, (int)__popcll(m));
        base = __shfl(base, leader);
        int pos = base + (int)__popcll(m & ((1ull << lane) - 1ull));
        if (pos < 512)
          cand[pos] = ((u64)__float_as_uint(v.x) << 32) | (u32)(~(u32)(2 * i));
      }
    }
    {
      bool p = min(255, (int)(v.y * 256.0f)) >= Bs;
      u64 m = __ballot(p);
      if (p) {
        int leader = (int)(__ffsll((long long)m) - 1);
        int base = 0;
        if (lane == leader) base = atomicAdd(&ctr, (int)__popcll(m));
        base = __shfl(base, leader);
        int pos = base + (int)__popcll(m & ((1ull << lane) - 1ull));
        if (pos < 512)
          cand[pos] = ((u64)__float_as_uint(v.y) << 32) | (u32)(~(u32)(2 * i + 1));
      }
    }
  }
  __syncthreads();
  int n = ctr < 512 ? ctr : 512;
  for (int i = n + tid; i < 512; i += 512) cand[i] = 0;  // pad sorts low
  __syncthreads();
  // bitonic sort 512 ascending, 1 element per thread
  for (int k = 2; k <= 512; k <<= 1) {
    for (int j = k >> 1; j > 0; j >>= 1) {
      int l = tid ^ j;
      if (l > tid) {
        u64 x = cand[tid], y = cand[l];
        bool asc = ((tid & k) == 0);
        if ((x > y) == asc) { cand[tid] = y; cand[l] = x; }
      }
      __syncthreads();
    }
  }
  if (tid < KSEL) {
    u64 kk = cand[511 - tid];
    tks[(size_t)row * KSEL + tid] = __uint_as_float((u32)(kk >> 32));
    tki[(size_t)row * KSEL + tid] = (int)(~(u32)kk);
  }
}

// ---------------- helpers ----------------
__device__ inline float rdlane(float x, int l) {
  return __int_as_float(__builtin_amdgcn_readlane(__float_as_int(x), l));
}

__device__ inline float4 decode1(const float* __restrict__ enc,
                                 const float* __restrict__ anch, int b, int ai) {
  float4 e  = ((const float4*)enc)[(size_t)b * AA + ai];
  float4 an = ((const float4*)anch)[ai];
  float ty = e.x / 10.0f, tx = e.y / 10.0f, th = e.z / 5.0f, tw = e.w / 5.0f;
  float yc = ty * an.z + an.x;
  float xc = tx * an.w + an.y;
  float h  = expf(th) * an.z;
  float w  = expf(tw) * an.w;
  float4 o;
  o.x = yc - h * 0.5f; o.y = xc - w * 0.5f; o.z = yc + h * 0.5f; o.w = xc + w * 0.5f;
  return o;
}

// ---------------- NMS v5: 4 independent rows interleaved per wave ----------
// Same exact algorithm as v4 (sorted-scan, f64-exact divide-free IoU test,
// register-captured output). One wave owns RPW=4 rows; the 4 serial chains
// are independent within a step so their latency bubbles hide each other.
// Branchless per-row guards (dead row: masks stay 0, captures disabled).
__global__ void __launch_bounds__(256) k_nms(const float* __restrict__ enc,
    const float* __restrict__ anch,
    const float* __restrict__ tks, const int* __restrict__ tki,
    float* __restrict__ flat_s, float* __restrict__ flat_b) {
  int wid = threadIdx.x >> 6, lane = threadIdx.x & 63;
  int wave = blockIdx.x * 4 + wid;
  float  s[RPW][4];
  float4 B[RPW][4];
  float  ar[RPW][4];
  u64    m0[RPW], m1[RPW], m2[RPW], m3[RPW];
  float  os0[RPW], os1[RPW];
  float4 ob0[RPW], ob1[RPW];
#pragma unroll
  for (int r = 0; r < RPW; r++) {
    int row = wave * RPW + r;
    int b = row / NCLS;
    const float* trow = tks + (size_t)row * KSEL;
    const int*   irow = tki + (size_t)row * KSEL;
#pragma unroll
    for (int k = 0; k < 4; k++) {
      s[r][k] = trow[64 * k + lane];
      int ai  = irow[64 * k + lane];
      B[r][k] = decode1(enc, anch, b, ai);
      ar[r][k] = (B[r][k].z - B[r][k].x) * (B[r][k].w - B[r][k].y);
    }
    m0[r] = __ballot(s[r][0] > 0.0f);
    m1[r] = __ballot(s[r][1] > 0.0f);
    m2[r] = __ballot(s[r][2] > 0.0f);
    m3[r] = __ballot(s[r][3] > 0.0f);
    os0[r] = 0.0f; os1[r] = 0.0f;
    ob0[r].x = ob0[r].y = ob0[r].z = ob0[r].w = 0.0f;
    ob1[r] = ob0[r];
  }
  // exact threshold midpoint: RN_f32(q) >= 0.6f  <=>  q >= M (f64 exact)
  const float cP = __uint_as_float(0x3F199999u);   // pred(0.6f)
  const double M = 0.5 * ((double)cP + (double)0.6f);
  for (int d = 0; d < MAXDET; d++) {
    u64 anyw = 0;
#pragma unroll
    for (int r = 0; r < RPW; r++) {
      u64 x0 = m0[r], x1 = m1[r], x2 = m2[r], x3 = m3[r];
      u64 wa = x0 ? x0 : x1; int ba = x0 ? 0 : 64;
      u64 wb = x2 ? x2 : x3; int bb2 = x2 ? 128 : 192;
      bool hi = (x0 | x1) != 0;
      u64 w = hi ? wa : wb;
      int base = hi ? ba : bb2;
      bool alive = (w != 0);
      u64 wsafe = alive ? w : 1ull;
      int pw = base + (int)__builtin_ctzll(wsafe);
      int kk = pw >> 6, lw = pw & 63;
      float cs = (kk == 0) ? s[r][0] : (kk == 1) ? s[r][1] : (kk == 2) ? s[r][2] : s[r][3];
      float cx = (kk == 0) ? B[r][0].x : (kk == 1) ? B[r][1].x : (kk == 2) ? B[r][2].x : B[r][3].x;
      float cy = (kk == 0) ? B[r][0].y : (kk == 1) ? B[r][1].y : (kk == 2) ? B[r][2].y : B[r][3].y;
      float cz = (kk == 0) ? B[r][0].z : (kk == 1) ? B[r][1].z : (kk == 2) ? B[r][2].z : B[r][3].z;
      float cw = (kk == 0) ? B[r][0].w : (kk == 1) ? B[r][1].w : (kk == 2) ? B[r][2].w : B[r][3].w;
      float sw_ = rdlane(cs, lw);
      float wx_ = rdlane(cx, lw);
      float wy_ = rdlane(cy, lw);
      float wz_ = rdlane(cz, lw);
      float ww_ = rdlane(cw, lw);
      bool c0 = alive && (lane == d);
      bool c1 = alive && (lane + 64 == d);
      os0[r] = c0 ? sw_ : os0[r];
      ob0[r].x = c0 ? wx_ : ob0[r].x; ob0[r].y = c0 ? wy_ : ob0[r].y;
      ob0[r].z = c0 ? wz_ : ob0[r].z; ob0[r].w = c0 ? ww_ : ob0[r].w;
      os1[r] = c1 ? sw_ : os1[r];
      ob1[r].x = c1 ? wx_ : ob1[r].x; ob1[r].y = c1 ? wy_ : ob1[r].y;
      ob1[r].z = c1 ? wz_ : ob1[r].z; ob1[r].w = c1 ? ww_ : ob1[r].w;
      float ia = (wz_ - wx_) * (ww_ - wy_);
      float in0, in1, in2, in3, un0, un1, un2, un3;
#define PAIR(K, INK, UNK) { \
        float ty = fmaxf(wx_, B[r][K].x), tx = fmaxf(wy_, B[r][K].y); \
        float by = fminf(wz_, B[r][K].z), bw = fminf(ww_, B[r][K].w); \
        float hh = fmaxf(by - ty, 0.0f), wvv = fmaxf(bw - tx, 0.0f); \
        INK = hh * wvv; \
        UNK = fmaxf(ia + ar[r][K] - INK, 1e-8f); }
      PAIR(0, in0, un0)
      PAIR(1, in1, un1)
      PAIR(2, in2, un2)
      PAIR(3, in3, un3)
#undef PAIR
      u64 cm0 = __ballot((double)in0 >= M * (double)un0);
      u64 cm1 = __ballot((double)in1 >= M * (double)un1);
      u64 cm2 = __ballot((double)in2 >= M * (double)un2);
      u64 cm3 = __ballot((double)in3 >= M * (double)un3);
      // dead row: masks already 0, &=~garbage keeps 0 (safe, branchless)
      m0[r] &= ~cm0; m1[r] &= ~cm1; m2[r] &= ~cm2; m3[r] &= ~cm3;
      anyw |= w;
    }
    if (!anyw) break;
  }
#pragma unroll
  for (int r = 0; r < RPW; r++) {
    int row = wave * RPW + r;
    int b = row / NCLS, c = row % NCLS;
    size_t fo = (size_t)b * NFLAT + (size_t)c * MAXDET;
    flat_s[fo + lane] = os0[r];
    ((float4*)flat_b)[fo + lane] = ob0[r];
    if (lane < MAXDET - 64) {
      flat_s[fo + 64 + lane] = os1[r];
      ((float4*)flat_b)[fo + 64 + lane] = ob1[r];
    }
  }
}

// ---------------- bitonic sorts (block of 256 threads) ----------------
__device__ inline void bitonic_u64_asc(u64* a, int n, int tid) {
  for (int k = 2; k <= n; k <<= 1) {
    for (int j = k >> 1; j > 0; j >>= 1) {
      for (int i = tid; i < n; i += 256) {
        int l = i ^ j;
        if (l > i) {
          u64 x = a[i], y = a[l];
          bool asc = ((i & k) == 0);
          if ((x > y) == asc) { a[i] = y; a[l] = x; }
        }
      }
      __syncthreads();
    }
  }
}
__device__ inline void bitonic_u32_asc(u32* a, int n, int tid) {
  for (int k = 2; k <= n; k <<= 1) {
    for (int j = k >> 1; j > 0; j >>= 1) {
      for (int i = tid; i < n; i += 256) {
        int l = i ^ j;
        if (l > i) {
          u32 x = a[i], y = a[l];
          bool asc = ((i & k) == 0);
          if ((x > y) == asc) { a[i] = y; a[l] = x; }
        }
      }
      __syncthreads();
    }
  }
}

// ---------------- exact radix select (rank kwant, descending) ----------------
template<typename F>
__device__ inline void radix_select(F getv, int n, int kwant,
    u32* hist, u32* suf, int* sh2, int tid,
    u32& V_out, int& GT_out, int& r_out) {
  int r = kwant; u32 V = 0; int GT = 0;
  for (int lvl = 0; lvl < 3; lvl++) {
    int shift = (lvl == 0) ? 19 : ((lvl == 1) ? 8 : 0);
    int nbins = (lvl == 2) ? 256 : 2048;
    for (int i = tid; i < nbins; i += 256) hist[i] = 0;
    __syncthreads();
    for (int idx = tid; idx < n; idx += 256) {
      u32 u = __float_as_uint(getv(idx));
      bool ok = (lvl == 0) || (lvl == 1 ? ((u >> 19) == (V >> 19))
                                        : ((u >> 8)  == (V >> 8)));
      u64 zm = __ballot(ok && u == 0u);
      if (ok) {
        if (u == 0u) {
          if ((int)(threadIdx.x & 63) == (int)(__ffsll((long long)zm) - 1))
            atomicAdd(&hist[0], (u32)__popcll(zm));
        } else {
          atomicAdd(&hist[(u >> shift) & (u32)(nbins - 1)], 1u);
        }
      }
    }
    __syncthreads();
    int G = nbins >> 8;
    u32 ps = 0;
    for (int g = 0; g < G; g++) ps += hist[tid * G + g];
    suf[tid] = ps;
    __syncthreads();
    for (int off = 1; off < 256; off <<= 1) {
      u32 v = (tid + off < 256) ? suf[tid + off] : 0u;
      __syncthreads();
      suf[tid] += v;
      __syncthreads();
    }
    u32 sufnext = (tid < 255) ? suf[tid + 1] : 0u;
    if (suf[tid] >= (u32)r && sufnext < (u32)r) {
      u32 cum = sufnext; int kb = tid * G;
      for (int bin = tid * G + G - 1; bin >= tid * G; bin--) {
        cum += hist[bin];
        if (cum >= (u32)r) { kb = bin; break; }
      }
      sh2[0] = kb;
      sh2[1] = (int)(cum - hist[kb]);
    }
    __syncthreads();
    int kb = sh2[0], gt = sh2[1];
    r -= gt; GT += gt; V |= ((u32)kb) << shift;
    __syncthreads();
  }
  V_out = V; GT_out = GT; r_out = r;
}

// ---------------- fallback: direct strided top-256 (small ws only) ----------
__global__ void __launch_bounds__(256) k_topk_direct(const float* __restrict__ src,
    float* __restrict__ tks, int* __restrict__ tki) {
  __shared__ u32 hist[2048];
  __shared__ u32 suf[256];
  __shared__ int sh2[2];
  __shared__ u64 sel[KSEL];
  __shared__ u32 tie[512];
  __shared__ int cgt, ctie;
  int row = blockIdx.x, tid = threadIdx.x;
  int b = row / NCLS, c = row % NCLS;
  const float* base = src + (size_t)b * AA * CCH + (c + 1);
  auto getv = [&](int i) -> float {
    float x = base[(size_t)i * CCH]; return 1.0f / (1.0f + expf(-x));
  };
  u32 V; int GT, r;
  radix_select(getv, AA, KSEL, hist, suf, sh2, tid, V, GT, r);
  if (tid == 0) { cgt = 0; ctie = 0; }
  __syncthreads();
  for (int i = tid; i < AA; i += 256) {
    u32 u = __float_as_uint(getv(i));
    if (u > V) {
      int p = atomicAdd(&cgt, 1);
      sel[p] = ((u64)u << 32) | (u32)(~(u32)i);
    } else if (u == V) {
      int p = atomicAdd(&ctie, 1);
      if (p < 512) tie[p] = (u32)i;
    }
  }
  __syncthreads();
  int nt = ctie < 512 ? ctie : 512;
  for (int i = tid + nt; i < 512; i += 256) tie[i] = 0xFFFFFFFFu;
  __syncthreads();
  bitonic_u32_asc(tie, 512, tid);
  for (int i = tid; i < r; i += 256)
    sel[GT + i] = ((u64)V << 32) | (u32)(~tie[i]);
  __syncthreads();
  bitonic_u64_asc(sel, KSEL, tid);
  for (int j = tid; j < KSEL; j += 256) {
    u64 kk = sel[KSEL - 1 - j];
    tks[(size_t)row * KSEL + j] = __uint_as_float((u32)(kk >> 32));
    tki[(size_t)row * KSEL + j] = (int)(~(u32)kk);
  }
}

// ---------------- final per-batch top-100: arith-bin + single sort ---------
__global__ void __launch_bounds__(512) k_final(const float* __restrict__ flat_s,
    const float* __restrict__ flat_b, float* __restrict__ out) {
  __shared__ u32 hist[256];
  __shared__ u32 suf[256];
  __shared__ u64 cand[512];
  __shared__ int shBs, ctr;
  int b = blockIdx.x, tid = threadIdx.x;
  int lane = tid & 63;
  const float2* src = (const float2*)(flat_s + (size_t)b * NFLAT);  // 9000 even
  if (tid < 256) hist[tid] = 0;
  if (tid == 0) ctr = 0;
  __syncthreads();
  for (int i = tid; i < NFLAT / 2; i += 512) {
    float2 v = src[i];
    atomicAdd(&hist[min(255, (int)(v.x * 256.0f))], 1u);
    atomicAdd(&hist[min(255, (int)(v.y * 256.0f))], 1u);
  }
  __syncthreads();
  if (tid < 256) suf[tid] = hist[tid];
  __syncthreads();
  for (int off = 1; off < 256; off <<= 1) {
    u32 v = 0;
    if (tid < 256 && tid + off < 256) v = suf[tid + off];
    __syncthreads();
    if (tid < 256) suf[tid] += v;
    __syncthreads();
  }
  if (tid < 256) {
    u32 nxt = (tid < 255) ? suf[tid + 1] : 0u;
    if (suf[tid] >= (u32)MAXDET && nxt < (u32)MAXDET) shBs = tid;
  }
  __syncthreads();
  int Bs = shBs;
  for (int i = tid; i < NFLAT / 2; i += 512) {
    float2 v = src[i];
    {
      bool p = min(255, (int)(v.x * 256.0f)) >= Bs;
      u64 m = __ballot(p);
      if (p) {
        int leader = (int)(__ffsll((long long)m) - 1);
        int base = 0;
        if (lane == leader) base = atomicAdd(&ctr, (int)__popcll(m));
        base = __shfl(base, leader);
        int pos = base + (int)__popcll(m & ((1ull << lane) - 1ull));
        if (pos < 512)
          cand[pos] = ((u64)__float_as_uint(v.x) << 32) | (u32)(~(u32)(2 * i));
      }
    }
    {
      bool p = min(255, (int)(v.y * 256.0f)) >= Bs;
      u64 m = __ballot(p);
      if (p) {
        int leader = (int)(__ffsll((long long)m) - 1);
        int base = 0;
        if (lane == leader) base = atomicAdd(&ctr, (int)__popcll(m));
        base = __shfl(base, leader);
        int pos = base + (int)__popcll(m & ((1ull << lane) - 1ull));
        if (pos < 512)
          cand[pos] = ((u64)__float_as_uint(v.y) << 32) | (u32)(~(u32)(2 * i + 1));
      }
    }
  }
  __syncthreads();
  int n = ctr < 512 ? ctr : 512;
  for (int i = n + tid; i < 512; i += 512) cand[i] = 0;  // pad sorts low
  __syncthreads();
  for (int k = 2; k <= 512; k <<= 1) {
    for (int j = k >> 1; j > 0; j >>= 1) {
      int l = tid ^ j;
      if (l > tid) {
        u64 x = cand[tid], y = cand[l];
        bool asc = ((tid & k) == 0);
        if ((x > y) == asc) { cand[tid] = y; cand[l] = x; }
      }
      __syncthreads();
    }
  }
  if (tid < MAXDET) {
    u64 kk = cand[511 - tid];
    u32 u  = (u32)(kk >> 32);
    int fi = (int)(~(u32)kk);
    float4 bb = ((const float4*)flat_b)[(size_t)b * NFLAT + fi];
    float* o = out + ((size_t)b * MAXDET + tid) * 6;
    o[0] = bb.x; o[1] = bb.y; o[2] = bb.z; o[3] = bb.w;
    o[4] = (float)(fi / 100 + 1);
    o[5] = __uint_as_float(u);
  }
}

// ---------------- launch ----------------
extern "C" void kernel_launch(void* const* d_in, const int* in_sizes, int n_in,
                              void* d_out, int out_size, void* d_ws, size_t ws_size,
                              hipStream_t stream) {
  const float* enc    = (const float*)d_in[0];
  const float* logits = (const float*)d_in[1];
  const float* anch   = (const float*)d_in[2];
  float* out = (float*)d_out;
  char* ws = (char*)d_ws;

  size_t off = 0;
  auto alloc = [&](size_t bytes) {
    size_t o = off;
    off += (bytes + 255) & ~(size_t)255;
    return o;
  };
  size_t o_tks  = alloc((size_t)NROWS * KSEL * 4);
  size_t o_tki  = alloc((size_t)NROWS * KSEL * 4);
  size_t o_fls  = alloc((size_t)BB * NFLAT * 4);
  size_t o_flb  = alloc((size_t)BB * NFLAT * 16);
  size_t need_base = off;
  size_t o_sc = off;                                   // chunked sc goes here
  size_t per_batch_sc = ((size_t)NCLS * AA * 4 + 255) & ~(size_t)255; // 6.92 MB

  int CB = 0;
  for (int cb = BB; cb >= 1; cb >>= 1) {
    if (ws_size >= need_base + (size_t)cb * per_batch_sc) { CB = cb; break; }
  }

  float* tks = (float*)(ws + o_tks);
  int*   tki = (int*)  (ws + o_tki);
  float* fls = (float*)(ws + o_fls);
  float* flb = (float*)(ws + o_flb);
  float* scp = (float*)(ws + o_sc);

  if (CB > 0) {
    for (int b0 = 0; b0 < BB; b0 += CB) {
      hipLaunchKernelGGL(k_sigT, dim3((AA + ATILE - 1) / ATILE, CB), dim3(256), 0,
                         stream, logits, scp, b0);
      hipLaunchKernelGGL(k_row, dim3(NCLS * CB), dim3(512), 0, stream,
                         scp, tks, tki, b0 * NCLS);
    }
  } else {
    hipLaunchKernelGGL(k_topk_direct, dim3(NROWS), dim3(256), 0, stream,
                       logits, tks, tki);
  }
  hipLaunchKernelGGL(k_nms, dim3(NROWS / (4 * RPW)), dim3(256), 0, stream,
                     enc, anch, tks, tki, fls, flb);
  hipLaunchKernelGGL(k_final, dim3(BB), dim3(512), 0, stream,
                     fls, flb, out);
}

// Round 14
// 169.039 us; speedup vs baseline: 1.4172x; 1.4172x over previous
//
#include <hip/hip_runtime.h>
#include <stdint.h>
#include <math.h>

typedef unsigned int u32;
typedef unsigned long long u64;

#define BB 8
#define AA 19206
#define CCH 91
#define NCLS 90
#define KSEL 256
#define MAXDET 100
#define NROWS (BB*NCLS)      // 720
#define NFLAT (NCLS*MAXDET)  // 9000
#define IOU_T 0.6f

// ---------------- sigmoid + transpose (per batch-chunk) ----------------
#define ATILE 64
__global__ void __launch_bounds__(256) k_sigT(const float* __restrict__ logits,
                                              float* __restrict__ sc, int b0) {
  __shared__ __align__(16) float tile[ATILE * CCH];  // 23.3 KB
  int bl = blockIdx.y;            // local batch within chunk
  int b  = b0 + bl;               // global batch
  int a0 = blockIdx.x * ATILE;
  int nt = AA - a0; if (nt > ATILE) nt = ATILE;
  int nload = nt * CCH;           // even
  const float* src = logits + ((size_t)b * AA + a0) * CCH;   // 8B aligned
  const float2* s2 = (const float2*)src;
  int n2 = nload >> 1;
  for (int i = threadIdx.x; i < n2; i += 256) ((float2*)tile)[i] = s2[i];
  __syncthreads();
  for (int j = threadIdx.x; j < ATILE * NCLS; j += 256) {
    int c  = j >> 6;       // whole wave shares c -> coalesced store
    int ai = j & 63;
    if (ai < nt) {
      float x = tile[ai * CCH + (c + 1)];
      float s = 1.0f / (1.0f + expf(-x));
      sc[((size_t)bl * NCLS + c) * AA + a0 + ai] = s;
    }
  }
}

// ---------------- per-row top-256: 2 global passes (L3-hot), small LDS ------
__global__ void __launch_bounds__(512) k_row(const float* __restrict__ sc,
    float* __restrict__ tks, int* __restrict__ tki, int row0) {
  __shared__ u32 hist[256];
  __shared__ u32 suf[256];
  __shared__ u64 cand[512];
  __shared__ int shBs, ctr;
  int rl  = blockIdx.x;
  int row = row0 + rl;
  int tid = threadIdx.x;
  const float2* src = (const float2*)(sc + (size_t)rl * AA);  // AA even
  if (tid < 256) hist[tid] = 0;
  if (tid == 0) ctr = 0;
  __syncthreads();
  for (int i = tid; i < AA / 2; i += 512) {
    float2 v = src[i];
    atomicAdd(&hist[min(255, (int)(v.x * 256.0f))], 1u);  // monotone bin
    atomicAdd(&hist[min(255, (int)(v.y * 256.0f))], 1u);
  }
  __syncthreads();
  if (tid < 256) suf[tid] = hist[tid];
  __syncthreads();
  for (int off = 1; off < 256; off <<= 1) {
    u32 v = 0;
    if (tid < 256 && tid + off < 256) v = suf[tid + off];
    __syncthreads();
    if (tid < 256) suf[tid] += v;
    __syncthreads();
  }
  if (tid < 256) {
    u32 nxt = (tid < 255) ? suf[tid + 1] : 0u;
    if (suf[tid] >= (u32)KSEL && nxt < (u32)KSEL) shBs = tid;
  }
  __syncthreads();
  int Bs = shBs;
  int lane = tid & 63;
  // pass 2: L2/L3-hot re-read, wave-aggregated LDS append of bins >= Bs
  for (int i = tid; i < AA / 2; i += 512) {
    float2 v = src[i];
    {
      bool p = min(255, (int)(v.x * 256.0f)) >= Bs;
      u64 m = __ballot(p);
      if (p) {
        int leader = (int)(__ffsll((long long)m) - 1);
        int base = 0;
        if (lane == leader) base = atomicAdd(&ctr, (int)__popcll(m));
        base = __shfl(base, leader);
        int pos = base + (int)__popcll(m & ((1ull << lane) - 1ull));
        if (pos < 512)
          cand[pos] = ((u64)__float_as_uint(v.x) << 32) | (u32)(~(u32)(2 * i));
      }
    }
    {
      bool p = min(255, (int)(v.y * 256.0f)) >= Bs;
      u64 m = __ballot(p);
      if (p) {
        int leader = (int)(__ffsll((long long)m) - 1);
        int base = 0;
        if (lane == leader) base = atomicAdd(&ctr, (int)__popcll(m));
        base = __shfl(base, leader);
        int pos = base + (int)__popcll(m & ((1ull << lane) - 1ull));
        if (pos < 512)
          cand[pos] = ((u64)__float_as_uint(v.y) << 32) | (u32)(~(u32)(2 * i + 1));
      }
    }
  }
  __syncthreads();
  int n = ctr < 512 ? ctr : 512;
  for (int i = n + tid; i < 512; i += 512) cand[i] = 0;  // pad sorts low
  __syncthreads();
  // bitonic sort 512 ascending, 1 element per thread
  for (int k = 2; k <= 512; k <<= 1) {
    for (int j = k >> 1; j > 0; j >>= 1) {
      int l = tid ^ j;
      if (l > tid) {
        u64 x = cand[tid], y = cand[l];
        bool asc = ((tid & k) == 0);
        if ((x > y) == asc) { cand[tid] = y; cand[l] = x; }
      }
      __syncthreads();
    }
  }
  if (tid < KSEL) {
    u64 kk = cand[511 - tid];
    tks[(size_t)row * KSEL + tid] = __uint_as_float((u32)(kk >> 32));
    tki[(size_t)row * KSEL + tid] = (int)(~(u32)kk);
  }
}

// ---------------- helpers ----------------
__device__ inline float rdlane(float x, int l) {
  return __int_as_float(__builtin_amdgcn_readlane(__float_as_int(x), l));
}

__device__ inline float4 decode1(const float* __restrict__ enc,
                                 const float* __restrict__ anch, int b, int ai) {
  float4 e  = ((const float4*)enc)[(size_t)b * AA + ai];
  float4 an = ((const float4*)anch)[ai];
  float ty = e.x / 10.0f, tx = e.y / 10.0f, th = e.z / 5.0f, tw = e.w / 5.0f;
  float yc = ty * an.z + an.x;
  float xc = tx * an.w + an.y;
  float h  = expf(th) * an.z;
  float w  = expf(tw) * an.w;
  float4 o;
  o.x = yc - h * 0.5f; o.y = xc - w * 0.5f; o.z = yc + h * 0.5f; o.w = xc + w * 0.5f;
  return o;
}

// ---------------- NMS v6: 2 independent rows per wave, scalar state --------
// v4's exact algorithm; two rows' dependent chains interleave to hide
// latency bubbles. State held in flat structs (scalars only -> SROA to
// registers); __launch_bounds__(256,1) lets the allocator use full budget.
struct Row {
  float s0, s1, s2, s3;
  float4 B0, B1, B2, B3;
  float a0, a1, a2, a3;
  u64 m0, m1, m2, m3;
  float os0, os1;
  float4 ob0, ob1;
};

__device__ __forceinline__ void row_init(Row& R,
    const float* __restrict__ tks, const int* __restrict__ tki,
    const float* __restrict__ enc, const float* __restrict__ anch,
    int row, int lane) {
  int b = row / NCLS;
  const float* trow = tks + (size_t)row * KSEL;
  const int*   irow = tki + (size_t)row * KSEL;
  R.s0 = trow[lane];       R.s1 = trow[64 + lane];
  R.s2 = trow[128 + lane]; R.s3 = trow[192 + lane];
  int i0 = irow[lane],       i1 = irow[64 + lane];
  int i2 = irow[128 + lane], i3 = irow[192 + lane];
  R.B0 = decode1(enc, anch, b, i0);
  R.B1 = decode1(enc, anch, b, i1);
  R.B2 = decode1(enc, anch, b, i2);
  R.B3 = decode1(enc, anch, b, i3);
  R.a0 = (R.B0.z - R.B0.x) * (R.B0.w - R.B0.y);
  R.a1 = (R.B1.z - R.B1.x) * (R.B1.w - R.B1.y);
  R.a2 = (R.B2.z - R.B2.x) * (R.B2.w - R.B2.y);
  R.a3 = (R.B3.z - R.B3.x) * (R.B3.w - R.B3.y);
  R.m0 = __ballot(R.s0 > 0.0f);
  R.m1 = __ballot(R.s1 > 0.0f);
  R.m2 = __ballot(R.s2 > 0.0f);
  R.m3 = __ballot(R.s3 > 0.0f);
  R.os0 = 0.0f; R.os1 = 0.0f;
  R.ob0.x = R.ob0.y = R.ob0.z = R.ob0.w = 0.0f;
  R.ob1 = R.ob0;
}

__device__ __forceinline__ u64 row_step(Row& R, int d, int lane, double M) {
  u64 x0 = R.m0, x1 = R.m1, x2 = R.m2, x3 = R.m3;
  u64 wa = x0 ? x0 : x1; int ba = x0 ? 0 : 64;
  u64 wb = x2 ? x2 : x3; int bb2 = x2 ? 128 : 192;
  bool hi = (x0 | x1) != 0;
  u64 w = hi ? wa : wb;
  int base = hi ? ba : bb2;
  bool alive = (w != 0);
  u64 wsafe = alive ? w : 1ull;
  int pw = base + (int)__builtin_ctzll(wsafe);
  int kk = pw >> 6, lw = pw & 63;
  float cs = (kk == 0) ? R.s0   : (kk == 1) ? R.s1   : (kk == 2) ? R.s2   : R.s3;
  float cx = (kk == 0) ? R.B0.x : (kk == 1) ? R.B1.x : (kk == 2) ? R.B2.x : R.B3.x;
  float cy = (kk == 0) ? R.B0.y : (kk == 1) ? R.B1.y : (kk == 2) ? R.B2.y : R.B3.y;
  float cz = (kk == 0) ? R.B0.z : (kk == 1) ? R.B1.z : (kk == 2) ? R.B2.z : R.B3.z;
  float cw = (kk == 0) ? R.B0.w : (kk == 1) ? R.B1.w : (kk == 2) ? R.B2.w : R.B3.w;
  float sw_ = rdlane(cs, lw);
  float wx_ = rdlane(cx, lw);
  float wy_ = rdlane(cy, lw);
  float wz_ = rdlane(cz, lw);
  float ww_ = rdlane(cw, lw);
  bool c0 = alive && (lane == d);
  bool c1 = alive && (lane + 64 == d);
  R.os0 = c0 ? sw_ : R.os0;
  R.ob0.x = c0 ? wx_ : R.ob0.x; R.ob0.y = c0 ? wy_ : R.ob0.y;
  R.ob0.z = c0 ? wz_ : R.ob0.z; R.ob0.w = c0 ? ww_ : R.ob0.w;
  R.os1 = c1 ? sw_ : R.os1;
  R.ob1.x = c1 ? wx_ : R.ob1.x; R.ob1.y = c1 ? wy_ : R.ob1.y;
  R.ob1.z = c1 ? wz_ : R.ob1.z; R.ob1.w = c1 ? ww_ : R.ob1.w;
  float ia = (wz_ - wx_) * (ww_ - wy_);
  float in0, in1, in2, in3, un0, un1, un2, un3;
#define PAIR(BX, AK, INK, UNK) { \
    float ty = fmaxf(wx_, BX.x), tx = fmaxf(wy_, BX.y); \
    float by = fminf(wz_, BX.z), bw = fminf(ww_, BX.w); \
    float hh = fmaxf(by - ty, 0.0f), wvv = fmaxf(bw - tx, 0.0f); \
    INK = hh * wvv; \
    UNK = fmaxf(ia + AK - INK, 1e-8f); }
  PAIR(R.B0, R.a0, in0, un0)
  PAIR(R.B1, R.a1, in1, un1)
  PAIR(R.B2, R.a2, in2, un2)
  PAIR(R.B3, R.a3, in3, un3)
#undef PAIR
  u64 cm0 = __ballot((double)in0 >= M * (double)un0);
  u64 cm1 = __ballot((double)in1 >= M * (double)un1);
  u64 cm2 = __ballot((double)in2 >= M * (double)un2);
  u64 cm3 = __ballot((double)in3 >= M * (double)un3);
  // dead row: masks already 0, &=~garbage keeps 0 (safe, branchless)
  R.m0 &= ~cm0; R.m1 &= ~cm1; R.m2 &= ~cm2; R.m3 &= ~cm3;
  return w;
}

__device__ __forceinline__ void row_store(const Row& R, int row, int lane,
    float* __restrict__ flat_s, float* __restrict__ flat_b) {
  int b = row / NCLS, c = row % NCLS;
  size_t fo = (size_t)b * NFLAT + (size_t)c * MAXDET;
  flat_s[fo + lane] = R.os0;
  ((float4*)flat_b)[fo + lane] = R.ob0;
  if (lane < MAXDET - 64) {
    flat_s[fo + 64 + lane] = R.os1;
    ((float4*)flat_b)[fo + 64 + lane] = R.ob1;
  }
}

__global__ void __launch_bounds__(256, 1) k_nms(const float* __restrict__ enc,
    const float* __restrict__ anch,
    const float* __restrict__ tks, const int* __restrict__ tki,
    float* __restrict__ flat_s, float* __restrict__ flat_b) {
  int wid = threadIdx.x >> 6, lane = threadIdx.x & 63;
  int wave = blockIdx.x * 4 + wid;
  int rowA = wave * 2, rowB = wave * 2 + 1;
  Row RA, RB;
  row_init(RA, tks, tki, enc, anch, rowA, lane);
  row_init(RB, tks, tki, enc, anch, rowB, lane);
  const float cP = __uint_as_float(0x3F199999u);   // pred(0.6f)
  const double M = 0.5 * ((double)cP + (double)0.6f);
  for (int d = 0; d < MAXDET; d++) {
    u64 wA = row_step(RA, d, lane, M);
    u64 wB = row_step(RB, d, lane, M);
    if (!(wA | wB)) break;
  }
  row_store(RA, rowA, lane, flat_s, flat_b);
  row_store(RB, rowB, lane, flat_s, flat_b);
}

// ---------------- bitonic sorts (block of 256 threads) ----------------
__device__ inline void bitonic_u64_asc(u64* a, int n, int tid) {
  for (int k = 2; k <= n; k <<= 1) {
    for (int j = k >> 1; j > 0; j >>= 1) {
      for (int i = tid; i < n; i += 256) {
        int l = i ^ j;
        if (l > i) {
          u64 x = a[i], y = a[l];
          bool asc = ((i & k) == 0);
          if ((x > y) == asc) { a[i] = y; a[l] = x; }
        }
      }
      __syncthreads();
    }
  }
}
__device__ inline void bitonic_u32_asc(u32* a, int n, int tid) {
  for (int k = 2; k <= n; k <<= 1) {
    for (int j = k >> 1; j > 0; j >>= 1) {
      for (int i = tid; i < n; i += 256) {
        int l = i ^ j;
        if (l > i) {
          u32 x = a[i], y = a[l];
          bool asc = ((i & k) == 0);
          if ((x > y) == asc) { a[i] = y; a[l] = x; }
        }
      }
      __syncthreads();
    }
  }
}

// ---------------- exact radix select (rank kwant, descending) ----------------
template<typename F>
__device__ inline void radix_select(F getv, int n, int kwant,
    u32* hist, u32* suf, int* sh2, int tid,
    u32& V_out, int& GT_out, int& r_out) {
  int r = kwant; u32 V = 0; int GT = 0;
  for (int lvl = 0; lvl < 3; lvl++) {
    int shift = (lvl == 0) ? 19 : ((lvl == 1) ? 8 : 0);
    int nbins = (lvl == 2) ? 256 : 2048;
    for (int i = tid; i < nbins; i += 256) hist[i] = 0;
    __syncthreads();
    for (int idx = tid; idx < n; idx += 256) {
      u32 u = __float_as_uint(getv(idx));
      bool ok = (lvl == 0) || (lvl == 1 ? ((u >> 19) == (V >> 19))
                                        : ((u >> 8)  == (V >> 8)));
      u64 zm = __ballot(ok && u == 0u);
      if (ok) {
        if (u == 0u) {
          if ((int)(threadIdx.x & 63) == (int)(__ffsll((long long)zm) - 1))
            atomicAdd(&hist[0], (u32)__popcll(zm));
        } else {
          atomicAdd(&hist[(u >> shift) & (u32)(nbins - 1)], 1u);
        }
      }
    }
    __syncthreads();
    int G = nbins >> 8;
    u32 ps = 0;
    for (int g = 0; g < G; g++) ps += hist[tid * G + g];
    suf[tid] = ps;
    __syncthreads();
    for (int off = 1; off < 256; off <<= 1) {
      u32 v = (tid + off < 256) ? suf[tid + off] : 0u;
      __syncthreads();
      suf[tid] += v;
      __syncthreads();
    }
    u32 sufnext = (tid < 255) ? suf[tid + 1] : 0u;
    if (suf[tid] >= (u32)r && sufnext < (u32)r) {
      u32 cum = sufnext; int kb = tid * G;
      for (int bin = tid * G + G - 1; bin >= tid * G; bin--) {
        cum += hist[bin];
        if (cum >= (u32)r) { kb = bin; break; }
      }
      sh2[0] = kb;
      sh2[1] = (int)(cum - hist[kb]);
    }
    __syncthreads();
    int kb = sh2[0], gt = sh2[1];
    r -= gt; GT += gt; V |= ((u32)kb) << shift;
    __syncthreads();
  }
  V_out = V; GT_out = GT; r_out = r;
}

// ---------------- fallback: direct strided top-256 (small ws only) ----------
__global__ void __launch_bounds__(256) k_topk_direct(const float* __restrict__ src,
    float* __restrict__ tks, int* __restrict__ tki) {
  __shared__ u32 hist[2048];
  __shared__ u32 suf[256];
  __shared__ int sh2[2];
  __shared__ u64 sel[KSEL];
  __shared__ u32 tie[512];
  __shared__ int cgt, ctie;
  int row = blockIdx.x, tid = threadIdx.x;
  int b = row / NCLS, c = row % NCLS;
  const float* base = src + (size_t)b * AA * CCH + (c + 1);
  auto getv = [&](int i) -> float {
    float x = base[(size_t)i * CCH]; return 1.0f / (1.0f + expf(-x));
  };
  u32 V; int GT, r;
  radix_select(getv, AA, KSEL, hist, suf, sh2, tid, V, GT, r);
  if (tid == 0) { cgt = 0; ctie = 0; }
  __syncthreads();
  for (int i = tid; i < AA; i += 256) {
    u32 u = __float_as_uint(getv(i));
    if (u > V) {
      int p = atomicAdd(&cgt, 1);
      sel[p] = ((u64)u << 32) | (u32)(~(u32)i);
    } else if (u == V) {
      int p = atomicAdd(&ctie, 1);
      if (p < 512) tie[p] = (u32)i;
    }
  }
  __syncthreads();
  int nt = ctie < 512 ? ctie : 512;
  for (int i = tid + nt; i < 512; i += 256) tie[i] = 0xFFFFFFFFu;
  __syncthreads();
  bitonic_u32_asc(tie, 512, tid);
  for (int i = tid; i < r; i += 256)
    sel[GT + i] = ((u64)V << 32) | (u32)(~tie[i]);
  __syncthreads();
  bitonic_u64_asc(sel, KSEL, tid);
  for (int j = tid; j < KSEL; j += 256) {
    u64 kk = sel[KSEL - 1 - j];
    tks[(size_t)row * KSEL + j] = __uint_as_float((u32)(kk >> 32));
    tki[(size_t)row * KSEL + j] = (int)(~(u32)kk);
  }
}

// ---------------- final per-batch top-100: arith-bin + single sort ---------
__global__ void __launch_bounds__(512) k_final(const float* __restrict__ flat_s,
    const float* __restrict__ flat_b, float* __restrict__ out) {
  __shared__ u32 hist[256];
  __shared__ u32 suf[256];
  __shared__ u64 cand[512];
  __shared__ int shBs, ctr;
  int b = blockIdx.x, tid = threadIdx.x;
  int lane = tid & 63;
  const float2* src = (const float2*)(flat_s + (size_t)b * NFLAT);  // 9000 even
  if (tid < 256) hist[tid] = 0;
  if (tid == 0) ctr = 0;
  __syncthreads();
  for (int i = tid; i < NFLAT / 2; i += 512) {
    float2 v = src[i];
    atomicAdd(&hist[min(255, (int)(v.x * 256.0f))], 1u);
    atomicAdd(&hist[min(255, (int)(v.y * 256.0f))], 1u);
  }
  __syncthreads();
  if (tid < 256) suf[tid] = hist[tid];
  __syncthreads();
  for (int off = 1; off < 256; off <<= 1) {
    u32 v = 0;
    if (tid < 256 && tid + off < 256) v = suf[tid + off];
    __syncthreads();
    if (tid < 256) suf[tid] += v;
    __syncthreads();
  }
  if (tid < 256) {
    u32 nxt = (tid < 255) ? suf[tid + 1] : 0u;
    if (suf[tid] >= (u32)MAXDET && nxt < (u32)MAXDET) shBs = tid;
  }
  __syncthreads();
  int Bs = shBs;
  for (int i = tid; i < NFLAT / 2; i += 512) {
    float2 v = src[i];
    {
      bool p = min(255, (int)(v.x * 256.0f)) >= Bs;
      u64 m = __ballot(p);
      if (p) {
        int leader = (int)(__ffsll((long long)m) - 1);
        int base = 0;
        if (lane == leader) base = atomicAdd(&ctr, (int)__popcll(m));
        base = __shfl(base, leader);
        int pos = base + (int)__popcll(m & ((1ull << lane) - 1ull));
        if (pos < 512)
          cand[pos] = ((u64)__float_as_uint(v.x) << 32) | (u32)(~(u32)(2 * i));
      }
    }
    {
      bool p = min(255, (int)(v.y * 256.0f)) >= Bs;
      u64 m = __ballot(p);
      if (p) {
        int leader = (int)(__ffsll((long long)m) - 1);
        int base = 0;
        if (lane == leader) base = atomicAdd(&ctr, (int)__popcll(m));
        base = __shfl(base, leader);
        int pos = base + (int)__popcll(m & ((1ull << lane) - 1ull));
        if (pos < 512)
          cand[pos] = ((u64)__float_as_uint(v.y) << 32) | (u32)(~(u32)(2 * i + 1));
      }
    }
  }
  __syncthreads();
  int n = ctr < 512 ? ctr : 512;
  for (int i = n + tid; i < 512; i += 512) cand[i] = 0;  // pad sorts low
  __syncthreads();
  for (int k = 2; k <= 512; k <<= 1) {
    for (int j = k >> 1; j > 0; j >>= 1) {
      int l = tid ^ j;
      if (l > tid) {
        u64 x = cand[tid], y = cand[l];
        bool asc = ((tid & k) == 0);
        if ((x > y) == asc) { cand[tid] = y; cand[l] = x; }
      }
      __syncthreads();
    }
  }
  if (tid < MAXDET) {
    u64 kk = cand[511 - tid];
    u32 u  = (u32)(kk >> 32);
    int fi = (int)(~(u32)kk);
    float4 bb = ((const float4*)flat_b)[(size_t)b * NFLAT + fi];
    float* o = out + ((size_t)b * MAXDET + tid) * 6;
    o[0] = bb.x; o[1] = bb.y; o[2] = bb.z; o[3] = bb.w;
    o[4] = (float)(fi / 100 + 1);
    o[5] = __uint_as_float(u);
  }
}

// ---------------- launch ----------------
extern "C" void kernel_launch(void* const* d_in, const int* in_sizes, int n_in,
                              void* d_out, int out_size, void* d_ws, size_t ws_size,
                              hipStream_t stream) {
  const float* enc    = (const float*)d_in[0];
  const float* logits = (const float*)d_in[1];
  const float* anch   = (const float*)d_in[2];
  float* out = (float*)d_out;
  char* ws = (char*)d_ws;

  size_t off = 0;
  auto alloc = [&](size_t bytes) {
    size_t o = off;
    off += (bytes + 255) & ~(size_t)255;
    return o;
  };
  size_t o_tks  = alloc((size_t)NROWS * KSEL * 4);
  size_t o_tki  = alloc((size_t)NROWS * KSEL * 4);
  size_t o_fls  = alloc((size_t)BB * NFLAT * 4);
  size_t o_flb  = alloc((size_t)BB * NFLAT * 16);
  size_t need_base = off;
  size_t o_sc = off;                                   // chunked sc goes here
  size_t per_batch_sc = ((size_t)NCLS * AA * 4 + 255) & ~(size_t)255; // 6.92 MB

  int CB = 0;
  for (int cb = BB; cb >= 1; cb >>= 1) {
    if (ws_size >= need_base + (size_t)cb * per_batch_sc) { CB = cb; break; }
  }

  float* tks = (float*)(ws + o_tks);
  int*   tki = (int*)  (ws + o_tki);
  float* fls = (float*)(ws + o_fls);
  float* flb = (float*)(ws + o_flb);
  float* scp = (float*)(ws + o_sc);

  if (CB > 0) {
    for (int b0 = 0; b0 < BB; b0 += CB) {
      hipLaunchKernelGGL(k_sigT, dim3((AA + ATILE - 1) / ATILE, CB), dim3(256), 0,
                         stream, logits, scp, b0);
      hipLaunchKernelGGL(k_row, dim3(NCLS * CB), dim3(512), 0, stream,
                         scp, tks, tki, b0 * NCLS);
    }
  } else {
    hipLaunchKernelGGL(k_topk_direct, dim3(NROWS), dim3(256), 0, stream,
                       logits, tks, tki);
  }
  hipLaunchKernelGGL(k_nms, dim3(NROWS / 8), dim3(256), 0, stream,
                     enc, anch, tks, tki, fls, flb);
  hipLaunchKernelGGL(k_final, dim3(BB), dim3(512), 0, stream,
                     fls, flb, out);
}

// Round 15
// 155.255 us; speedup vs baseline: 1.5430x; 1.0888x over previous
//
#include <hip/hip_runtime.h>
#include <stdint.h>
#include <math.h>

typedef unsigned int u32;
typedef unsigned long long u64;

#define BB 8
#define AA 19206
#define CCH 91
#define NCLS 90
#define KSEL 256
#define MAXDET 100
#define NROWS (BB*NCLS)      // 720
#define NFLAT (NCLS*MAXDET)  // 9000
#define IOU_T 0.6f
#define NBIN 64              // score-histogram bins (bin = min(63, s*64))

// ---------------- sigmoid + transpose + fused 64-bin histogram -------------
#define ATILE 64
__global__ void __launch_bounds__(256) k_sigT(const float* __restrict__ logits,
    float* __restrict__ sc, u32* __restrict__ ghist, int b0) {
  __shared__ __align__(16) float tile[ATILE * CCH];  // 23.3 KB
  __shared__ u32 lhist[NCLS * 65];                   // 23.4 KB, stride 65 (bank-safe)
  int bl = blockIdx.y;            // local batch within chunk
  int b  = b0 + bl;               // global batch
  int a0 = blockIdx.x * ATILE;
  int nt = AA - a0; if (nt > ATILE) nt = ATILE;
  int nload = nt * CCH;           // even
  const float* src = logits + ((size_t)b * AA + a0) * CCH;   // 8B aligned
  const float2* s2 = (const float2*)src;
  int n2 = nload >> 1;
  for (int i = threadIdx.x; i < NCLS * 65; i += 256) lhist[i] = 0;
  for (int i = threadIdx.x; i < n2; i += 256) ((float2*)tile)[i] = s2[i];
  __syncthreads();
  for (int j = threadIdx.x; j < ATILE * NCLS; j += 256) {
    int c  = j >> 6;       // whole wave shares c -> coalesced store
    int ai = j & 63;
    if (ai < nt) {
      float x = tile[ai * CCH + (c + 1)];
      float s = 1.0f / (1.0f + expf(-x));
      sc[((size_t)bl * NCLS + c) * AA + a0 + ai] = s;
      atomicAdd(&lhist[c * 65 + min(63, (int)(s * 64.0f))], 1u);
    }
  }
  __syncthreads();
  int rowbase = b * NCLS;
  for (int i = threadIdx.x; i < NCLS * NBIN; i += 256) {
    int c = i >> 6, bin = i & 63;
    u32 v = lhist[c * 65 + bin];
    if (v) atomicAdd(&ghist[(size_t)(rowbase + c) * NBIN + bin], v);
  }
}

// ---------------- per-row threshold bin from global histogram --------------
__global__ void __launch_bounds__(64) k_thresh(const u32* __restrict__ ghist,
                                               int* __restrict__ gBs, int row0) {
  int row = row0 + blockIdx.x;
  int lane = threadIdx.x;
  u32 suf = ghist[(size_t)row * NBIN + lane];
  for (int off = 1; off < 64; off <<= 1) {
    u32 v = __shfl_down(suf, off);
    suf += (lane + off < 64) ? v : 0u;
  }
  u32 nxt = __shfl_down(suf, 1);
  if (lane == 63) nxt = 0u;
  if (suf >= (u32)KSEL && nxt < (u32)KSEL) gBs[row] = lane;
}

// ---------------- per-row top-256: single pass (compact + sort) ------------
__global__ void __launch_bounds__(512) k_row(const float* __restrict__ sc,
    const int* __restrict__ gBs,
    float* __restrict__ tks, int* __restrict__ tki, int row0) {
  __shared__ u64 cand[512];
  __shared__ int ctr;
  int rl  = blockIdx.x;
  int row = row0 + rl;
  int tid = threadIdx.x;
  const float2* src = (const float2*)(sc + (size_t)rl * AA);  // AA even
  if (tid == 0) ctr = 0;
  int Bs = gBs[row];
  __syncthreads();
  int lane = tid & 63;
  for (int i = tid; i < AA / 2; i += 512) {
    float2 v = src[i];
    {
      bool p = min(63, (int)(v.x * 64.0f)) >= Bs;
      u64 m = __ballot(p);
      if (p) {
        int leader = (int)(__ffsll((long long)m) - 1);
        int base = 0;
        if (lane == leader) base = atomicAdd(&ctr, (int)__popcll(m));
        base = __shfl(base, leader);
        int pos = base + (int)__popcll(m & ((1ull << lane) - 1ull));
        if (pos < 512)
          cand[pos] = ((u64)__float_as_uint(v.x) << 32) | (u32)(~(u32)(2 * i));
      }
    }
    {
      bool p = min(63, (int)(v.y * 64.0f)) >= Bs;
      u64 m = __ballot(p);
      if (p) {
        int leader = (int)(__ffsll((long long)m) - 1);
        int base = 0;
        if (lane == leader) base = atomicAdd(&ctr, (int)__popcll(m));
        base = __shfl(base, leader);
        int pos = base + (int)__popcll(m & ((1ull << lane) - 1ull));
        if (pos < 512)
          cand[pos] = ((u64)__float_as_uint(v.y) << 32) | (u32)(~(u32)(2 * i + 1));
      }
    }
  }
  __syncthreads();
  int n = ctr < 512 ? ctr : 512;
  for (int i = n + tid; i < 512; i += 512) cand[i] = 0;  // pad sorts low
  __syncthreads();
  // bitonic sort 512 ascending, 1 element per thread
  for (int k = 2; k <= 512; k <<= 1) {
    for (int j = k >> 1; j > 0; j >>= 1) {
      int l = tid ^ j;
      if (l > tid) {
        u64 x = cand[tid], y = cand[l];
        bool asc = ((tid & k) == 0);
        if ((x > y) == asc) { cand[tid] = y; cand[l] = x; }
      }
      __syncthreads();
    }
  }
  if (tid < KSEL) {
    u64 kk = cand[511 - tid];
    tks[(size_t)row * KSEL + tid] = __uint_as_float((u32)(kk >> 32));
    tki[(size_t)row * KSEL + tid] = (int)(~(u32)kk);
  }
}

// ---------------- helpers ----------------
__device__ inline float rdlane(float x, int l) {
  return __int_as_float(__builtin_amdgcn_readlane(__float_as_int(x), l));
}

__device__ inline float4 decode1(const float* __restrict__ enc,
                                 const float* __restrict__ anch, int b, int ai) {
  float4 e  = ((const float4*)enc)[(size_t)b * AA + ai];
  float4 an = ((const float4*)anch)[ai];
  float ty = e.x / 10.0f, tx = e.y / 10.0f, th = e.z / 5.0f, tw = e.w / 5.0f;
  float yc = ty * an.z + an.x;
  float xc = tx * an.w + an.y;
  float h  = expf(th) * an.z;
  float w  = expf(tw) * an.w;
  float4 o;
  o.x = yc - h * 0.5f; o.y = xc - w * 0.5f; o.z = yc + h * 0.5f; o.w = xc + w * 0.5f;
  return o;
}

// ---------------- NMS v4 (R12-verbatim): sorted-scan, exact IoU test -------
__global__ void __launch_bounds__(256) k_nms(const float* __restrict__ enc,
    const float* __restrict__ anch,
    const float* __restrict__ tks, const int* __restrict__ tki,
    float* __restrict__ flat_s, float* __restrict__ flat_b) {
  int wid = threadIdx.x >> 6, lane = threadIdx.x & 63;
  int row = blockIdx.x * 4 + wid;
  int b = row / NCLS, c = row % NCLS;
  const float* trow = tks + (size_t)row * KSEL;
  const int*   irow = tki + (size_t)row * KSEL;
  float s0 = trow[lane], s1 = trow[64 + lane], s2 = trow[128 + lane], s3 = trow[192 + lane];
  int   i0 = irow[lane], i1 = irow[64 + lane], i2 = irow[128 + lane], i3 = irow[192 + lane];
  float4 B0 = decode1(enc, anch, b, i0);
  float4 B1 = decode1(enc, anch, b, i1);
  float4 B2 = decode1(enc, anch, b, i2);
  float4 B3 = decode1(enc, anch, b, i3);
  float a0 = (B0.z - B0.x) * (B0.w - B0.y);
  float a1 = (B1.z - B1.x) * (B1.w - B1.y);
  float a2 = (B2.z - B2.x) * (B2.w - B2.y);
  float a3 = (B3.z - B3.x) * (B3.w - B3.y);
  u64 m0 = __ballot(s0 > 0.0f);
  u64 m1 = __ballot(s1 > 0.0f);
  u64 m2 = __ballot(s2 > 0.0f);
  u64 m3 = __ballot(s3 > 0.0f);
  // exact threshold midpoint: RN(q) >= 0.6f  <=>  q >= M
  const float cP = __uint_as_float(0x3F199999u);   // pred(0.6f)
  const double M = 0.5 * ((double)cP + (double)0.6f);
  float ss0 = 0.0f, ss1 = 0.0f;
  float4 ob0; ob0.x = ob0.y = ob0.z = ob0.w = 0.0f;
  float4 ob1 = ob0;
  size_t fo = (size_t)b * NFLAT + (size_t)c * MAXDET;
  for (int d = 0; d < MAXDET; d++) {
    int kw; u64 w;
    if      (m0) { kw = 0; w = m0; }
    else if (m1) { kw = 1; w = m1; }
    else if (m2) { kw = 2; w = m2; }
    else if (m3) { kw = 3; w = m3; }
    else break;
    int lw = (int)__builtin_ctzll(w);
    float sw_, wx_, wy_, wz_, ww_;
    if (kw == 0) {
      sw_ = rdlane(s0, lw);
      wx_ = rdlane(B0.x, lw); wy_ = rdlane(B0.y, lw);
      wz_ = rdlane(B0.z, lw); ww_ = rdlane(B0.w, lw);
    } else if (kw == 1) {
      sw_ = rdlane(s1, lw);
      wx_ = rdlane(B1.x, lw); wy_ = rdlane(B1.y, lw);
      wz_ = rdlane(B1.z, lw); ww_ = rdlane(B1.w, lw);
    } else if (kw == 2) {
      sw_ = rdlane(s2, lw);
      wx_ = rdlane(B2.x, lw); wy_ = rdlane(B2.y, lw);
      wz_ = rdlane(B2.z, lw); ww_ = rdlane(B2.w, lw);
    } else {
      sw_ = rdlane(s3, lw);
      wx_ = rdlane(B3.x, lw); wy_ = rdlane(B3.y, lw);
      wz_ = rdlane(B3.z, lw); ww_ = rdlane(B3.w, lw);
    }
    // register-buffered output capture (no divergent store)
    bool c0 = (lane == d);
    bool c1 = (lane + 64 == d);
    ss0 = c0 ? sw_ : ss0;
    ob0.x = c0 ? wx_ : ob0.x; ob0.y = c0 ? wy_ : ob0.y;
    ob0.z = c0 ? wz_ : ob0.z; ob0.w = c0 ? ww_ : ob0.w;
    ss1 = c1 ? sw_ : ss1;
    ob1.x = c1 ? wx_ : ob1.x; ob1.y = c1 ? wy_ : ob1.y;
    ob1.z = c1 ? wz_ : ob1.z; ob1.w = c1 ? ww_ : ob1.w;
    float ia = (wz_ - wx_) * (ww_ - wy_);
    float in0, in1, in2, in3, un0, un1, un2, un3;
#define PAIR(BX, AK, INK, UNK) { \
      float ty = fmaxf(wx_, BX.x), tx = fmaxf(wy_, BX.y); \
      float by = fminf(wz_, BX.z), bw = fminf(ww_, BX.w); \
      float hh = fmaxf(by - ty, 0.0f), wvv = fmaxf(bw - tx, 0.0f); \
      INK = hh * wvv; \
      UNK = fmaxf(ia + AK - INK, 1e-8f); }
    PAIR(B0, a0, in0, un0)
    PAIR(B1, a1, in1, un1)
    PAIR(B2, a2, in2, un2)
    PAIR(B3, a3, in3, un3)
#undef PAIR
    u64 cm0 = __ballot((double)in0 >= M * (double)un0);
    u64 cm1 = __ballot((double)in1 >= M * (double)un1);
    u64 cm2 = __ballot((double)in2 >= M * (double)un2);
    u64 cm3 = __ballot((double)in3 >= M * (double)un3);
    m0 &= ~cm0; m1 &= ~cm1; m2 &= ~cm2; m3 &= ~cm3;
  }
  flat_s[fo + lane] = ss0;
  ((float4*)flat_b)[fo + lane] = ob0;
  if (lane < MAXDET - 64) {
    flat_s[fo + 64 + lane] = ss1;
    ((float4*)flat_b)[fo + 64 + lane] = ob1;
  }
}

// ---------------- bitonic sorts (block of 256 threads) ----------------
__device__ inline void bitonic_u64_asc(u64* a, int n, int tid) {
  for (int k = 2; k <= n; k <<= 1) {
    for (int j = k >> 1; j > 0; j >>= 1) {
      for (int i = tid; i < n; i += 256) {
        int l = i ^ j;
        if (l > i) {
          u64 x = a[i], y = a[l];
          bool asc = ((i & k) == 0);
          if ((x > y) == asc) { a[i] = y; a[l] = x; }
        }
      }
      __syncthreads();
    }
  }
}
__device__ inline void bitonic_u32_asc(u32* a, int n, int tid) {
  for (int k = 2; k <= n; k <<= 1) {
    for (int j = k >> 1; j > 0; j >>= 1) {
      for (int i = tid; i < n; i += 256) {
        int l = i ^ j;
        if (l > i) {
          u32 x = a[i], y = a[l];
          bool asc = ((i & k) == 0);
          if ((x > y) == asc) { a[i] = y; a[l] = x; }
        }
      }
      __syncthreads();
    }
  }
}

// ---------------- exact radix select (rank kwant, descending) ----------------
template<typename F>
__device__ inline void radix_select(F getv, int n, int kwant,
    u32* hist, u32* suf, int* sh2, int tid,
    u32& V_out, int& GT_out, int& r_out) {
  int r = kwant; u32 V = 0; int GT = 0;
  for (int lvl = 0; lvl < 3; lvl++) {
    int shift = (lvl == 0) ? 19 : ((lvl == 1) ? 8 : 0);
    int nbins = (lvl == 2) ? 256 : 2048;
    for (int i = tid; i < nbins; i += 256) hist[i] = 0;
    __syncthreads();
    for (int idx = tid; idx < n; idx += 256) {
      u32 u = __float_as_uint(getv(idx));
      bool ok = (lvl == 0) || (lvl == 1 ? ((u >> 19) == (V >> 19))
                                        : ((u >> 8)  == (V >> 8)));
      u64 zm = __ballot(ok && u == 0u);
      if (ok) {
        if (u == 0u) {
          if ((int)(threadIdx.x & 63) == (int)(__ffsll((long long)zm) - 1))
            atomicAdd(&hist[0], (u32)__popcll(zm));
        } else {
          atomicAdd(&hist[(u >> shift) & (u32)(nbins - 1)], 1u);
        }
      }
    }
    __syncthreads();
    int G = nbins >> 8;
    u32 ps = 0;
    for (int g = 0; g < G; g++) ps += hist[tid * G + g];
    suf[tid] = ps;
    __syncthreads();
    for (int off = 1; off < 256; off <<= 1) {
      u32 v = (tid + off < 256) ? suf[tid + off] : 0u;
      __syncthreads();
      suf[tid] += v;
      __syncthreads();
    }
    u32 sufnext = (tid < 255) ? suf[tid + 1] : 0u;
    if (suf[tid] >= (u32)r && sufnext < (u32)r) {
      u32 cum = sufnext; int kb = tid * G;
      for (int bin = tid * G + G - 1; bin >= tid * G; bin--) {
        cum += hist[bin];
        if (cum >= (u32)r) { kb = bin; break; }
      }
      sh2[0] = kb;
      sh2[1] = (int)(cum - hist[kb]);
    }
    __syncthreads();
    int kb = sh2[0], gt = sh2[1];
    r -= gt; GT += gt; V |= ((u32)kb) << shift;
    __syncthreads();
  }
  V_out = V; GT_out = GT; r_out = r;
}

// ---------------- fallback: direct strided top-256 (small ws only) ----------
__global__ void __launch_bounds__(256) k_topk_direct(const float* __restrict__ src,
    float* __restrict__ tks, int* __restrict__ tki) {
  __shared__ u32 hist[2048];
  __shared__ u32 suf[256];
  __shared__ int sh2[2];
  __shared__ u64 sel[KSEL];
  __shared__ u32 tie[512];
  __shared__ int cgt, ctie;
  int row = blockIdx.x, tid = threadIdx.x;
  int b = row / NCLS, c = row % NCLS;
  const float* base = src + (size_t)b * AA * CCH + (c + 1);
  auto getv = [&](int i) -> float {
    float x = base[(size_t)i * CCH]; return 1.0f / (1.0f + expf(-x));
  };
  u32 V; int GT, r;
  radix_select(getv, AA, KSEL, hist, suf, sh2, tid, V, GT, r);
  if (tid == 0) { cgt = 0; ctie = 0; }
  __syncthreads();
  for (int i = tid; i < AA; i += 256) {
    u32 u = __float_as_uint(getv(i));
    if (u > V) {
      int p = atomicAdd(&cgt, 1);
      sel[p] = ((u64)u << 32) | (u32)(~(u32)i);
    } else if (u == V) {
      int p = atomicAdd(&ctie, 1);
      if (p < 512) tie[p] = (u32)i;
    }
  }
  __syncthreads();
  int nt = ctie < 512 ? ctie : 512;
  for (int i = tid + nt; i < 512; i += 256) tie[i] = 0xFFFFFFFFu;
  __syncthreads();
  bitonic_u32_asc(tie, 512, tid);
  for (int i = tid; i < r; i += 256)
    sel[GT + i] = ((u64)V << 32) | (u32)(~tie[i]);
  __syncthreads();
  bitonic_u64_asc(sel, KSEL, tid);
  for (int j = tid; j < KSEL; j += 256) {
    u64 kk = sel[KSEL - 1 - j];
    tks[(size_t)row * KSEL + j] = __uint_as_float((u32)(kk >> 32));
    tki[(size_t)row * KSEL + j] = (int)(~(u32)kk);
  }
}

// ---------------- final per-batch top-100: arith-bin + single sort ---------
__global__ void __launch_bounds__(512) k_final(const float* __restrict__ flat_s,
    const float* __restrict__ flat_b, float* __restrict__ out) {
  __shared__ u32 hist[256];
  __shared__ u32 suf[256];
  __shared__ u64 cand[512];
  __shared__ int shBs, ctr;
  int b = blockIdx.x, tid = threadIdx.x;
  int lane = tid & 63;
  const float2* src = (const float2*)(flat_s + (size_t)b * NFLAT);  // 9000 even
  if (tid < 256) hist[tid] = 0;
  if (tid == 0) ctr = 0;
  __syncthreads();
  for (int i = tid; i < NFLAT / 2; i += 512) {
    float2 v = src[i];
    atomicAdd(&hist[min(255, (int)(v.x * 256.0f))], 1u);
    atomicAdd(&hist[min(255, (int)(v.y * 256.0f))], 1u);
  }
  __syncthreads();
  if (tid < 256) suf[tid] = hist[tid];
  __syncthreads();
  for (int off = 1; off < 256; off <<= 1) {
    u32 v = 0;
    if (tid < 256 && tid + off < 256) v = suf[tid + off];
    __syncthreads();
    if (tid < 256) suf[tid] += v;
    __syncthreads();
  }
  if (tid < 256) {
    u32 nxt = (tid < 255) ? suf[tid + 1] : 0u;
    if (suf[tid] >= (u32)MAXDET && nxt < (u32)MAXDET) shBs = tid;
  }
  __syncthreads();
  int Bs = shBs;
  for (int i = tid; i < NFLAT / 2; i += 512) {
    float2 v = src[i];
    {
      bool p = min(255, (int)(v.x * 256.0f)) >= Bs;
      u64 m = __ballot(p);
      if (p) {
        int leader = (int)(__ffsll((long long)m) - 1);
        int base = 0;
        if (lane == leader) base = atomicAdd(&ctr, (int)__popcll(m));
        base = __shfl(base, leader);
        int pos = base + (int)__popcll(m & ((1ull << lane) - 1ull));
        if (pos < 512)
          cand[pos] = ((u64)__float_as_uint(v.x) << 32) | (u32)(~(u32)(2 * i));
      }
    }
    {
      bool p = min(255, (int)(v.y * 256.0f)) >= Bs;
      u64 m = __ballot(p);
      if (p) {
        int leader = (int)(__ffsll((long long)m) - 1);
        int base = 0;
        if (lane == leader) base = atomicAdd(&ctr, (int)__popcll(m));
        base = __shfl(base, leader);
        int pos = base + (int)__popcll(m & ((1ull << lane) - 1ull));
        if (pos < 512)
          cand[pos] = ((u64)__float_as_uint(v.y) << 32) | (u32)(~(u32)(2 * i + 1));
      }
    }
  }
  __syncthreads();
  int n = ctr < 512 ? ctr : 512;
  for (int i = n + tid; i < 512; i += 512) cand[i] = 0;  // pad sorts low
  __syncthreads();
  for (int k = 2; k <= 512; k <<= 1) {
    for (int j = k >> 1; j > 0; j >>= 1) {
      int l = tid ^ j;
      if (l > tid) {
        u64 x = cand[tid], y = cand[l];
        bool asc = ((tid & k) == 0);
        if ((x > y) == asc) { cand[tid] = y; cand[l] = x; }
      }
      __syncthreads();
    }
  }
  if (tid < MAXDET) {
    u64 kk = cand[511 - tid];
    u32 u  = (u32)(kk >> 32);
    int fi = (int)(~(u32)kk);
    float4 bb = ((const float4*)flat_b)[(size_t)b * NFLAT + fi];
    float* o = out + ((size_t)b * MAXDET + tid) * 6;
    o[0] = bb.x; o[1] = bb.y; o[2] = bb.z; o[3] = bb.w;
    o[4] = (float)(fi / 100 + 1);
    o[5] = __uint_as_float(u);
  }
}

// ---------------- launch ----------------
extern "C" void kernel_launch(void* const* d_in, const int* in_sizes, int n_in,
                              void* d_out, int out_size, void* d_ws, size_t ws_size,
                              hipStream_t stream) {
  const float* enc    = (const float*)d_in[0];
  const float* logits = (const float*)d_in[1];
  const float* anch   = (const float*)d_in[2];
  float* out = (float*)d_out;
  char* ws = (char*)d_ws;

  size_t off = 0;
  auto alloc = [&](size_t bytes) {
    size_t o = off;
    off += (bytes + 255) & ~(size_t)255;
    return o;
  };
  size_t o_tks  = alloc((size_t)NROWS * KSEL * 4);
  size_t o_tki  = alloc((size_t)NROWS * KSEL * 4);
  size_t o_fls  = alloc((size_t)BB * NFLAT * 4);
  size_t o_flb  = alloc((size_t)BB * NFLAT * 16);
  size_t o_gh   = alloc((size_t)NROWS * NBIN * 4);    // 184 KB global hist
  size_t o_gbs  = alloc((size_t)NROWS * 4);
  size_t need_base = off;
  size_t o_sc = off;                                   // chunked sc goes here
  size_t per_batch_sc = ((size_t)NCLS * AA * 4 + 255) & ~(size_t)255; // 6.92 MB

  int CB = 0;
  for (int cb = BB; cb >= 1; cb >>= 1) {
    if (ws_size >= need_base + (size_t)cb * per_batch_sc) { CB = cb; break; }
  }

  float* tks = (float*)(ws + o_tks);
  int*   tki = (int*)  (ws + o_tki);
  float* fls = (float*)(ws + o_fls);
  float* flb = (float*)(ws + o_flb);
  u32*   gh  = (u32*)  (ws + o_gh);
  int*   gbs = (int*)  (ws + o_gbs);
  float* scp = (float*)(ws + o_sc);

  if (CB > 0) {
    hipMemsetAsync(gh, 0, (size_t)NROWS * NBIN * 4, stream);
    for (int b0 = 0; b0 < BB; b0 += CB) {
      hipLaunchKernelGGL(k_sigT, dim3((AA + ATILE - 1) / ATILE, CB), dim3(256), 0,
                         stream, logits, scp, gh, b0);
      hipLaunchKernelGGL(k_thresh, dim3(NCLS * CB), dim3(64), 0, stream,
                         gh, gbs, b0 * NCLS);
      hipLaunchKernelGGL(k_row, dim3(NCLS * CB), dim3(512), 0, stream,
                         scp, gbs, tks, tki, b0 * NCLS);
    }
  } else {
    hipLaunchKernelGGL(k_topk_direct, dim3(NROWS), dim3(256), 0, stream,
                       logits, tks, tki);
  }
  hipLaunchKernelGGL(k_nms, dim3(NROWS / 4), dim3(256), 0, stream,
                     enc, anch, tks, tki, fls, flb);
  hipLaunchKernelGGL(k_final, dim3(BB), dim3(512), 0, stream,
                     fls, flb, out);
}

// Round 16
// 113.320 us; speedup vs baseline: 2.1141x; 1.3701x over previous
//
#include <hip/hip_runtime.h>
#include <stdint.h>
#include <math.h>

typedef unsigned int u32;
typedef unsigned long long u64;
typedef unsigned char u8;

#define BB 8
#define AA 19206
#define CCH 91
#define NCLS 90
#define KSEL 256
#define MAXDET 100
#define NROWS (BB*NCLS)      // 720
#define NFLAT (NCLS*MAXDET)  // 9000
#define IOU_T 0.6f

// ---------------- sigmoid + transpose (+ u8 bin sidecar) ----------------
#define ATILE 64
__global__ void __launch_bounds__(256) k_sigT(const float* __restrict__ logits,
    float* __restrict__ sc, u8* __restrict__ sbin, int b0) {
  __shared__ __align__(16) float tile[ATILE * CCH];  // 23.3 KB
  int bl = blockIdx.y;            // local batch within chunk
  int b  = b0 + bl;               // global batch
  int a0 = blockIdx.x * ATILE;
  int nt = AA - a0; if (nt > ATILE) nt = ATILE;
  int nload = nt * CCH;           // even
  const float* src = logits + ((size_t)b * AA + a0) * CCH;   // 8B aligned
  const float2* s2 = (const float2*)src;
  int n2 = nload >> 1;
  for (int i = threadIdx.x; i < n2; i += 256) ((float2*)tile)[i] = s2[i];
  __syncthreads();
  for (int j = threadIdx.x; j < ATILE * NCLS; j += 256) {
    int c  = j >> 6;       // whole wave shares c -> coalesced store
    int ai = j & 63;
    if (ai < nt) {
      float x = tile[ai * CCH + (c + 1)];
      float s = 1.0f / (1.0f + expf(-x));
      size_t o = ((size_t)bl * NCLS + c) * AA + a0 + ai;
      sc[o] = s;
      sbin[o] = (u8)min(255, (int)(s * 256.0f));
    }
  }
}

// ---------------- per-row top-256: u8-hist pass + compact+sort pass --------
__global__ void __launch_bounds__(512) k_row(const float* __restrict__ sc,
    const u8* __restrict__ sbin,
    float* __restrict__ tks, int* __restrict__ tki, int row0) {
  __shared__ u32 hist[256];
  __shared__ u32 suf[256];
  __shared__ u64 cand[512];
  __shared__ int shBs, ctr;
  int rl  = blockIdx.x;
  int row = row0 + rl;
  int tid = threadIdx.x;
  const float2* src = (const float2*)(sc + (size_t)rl * AA);     // AA even
  const uchar2* sb2 = (const uchar2*)(sbin + (size_t)rl * AA);   // 2B aligned
  if (tid < 256) hist[tid] = 0;
  if (tid == 0) ctr = 0;
  __syncthreads();
  // pass 1: histogram from u8 sidecar (1/4 the bytes of the f32 row)
  for (int i = tid; i < AA / 2; i += 512) {
    uchar2 bb = sb2[i];
    atomicAdd(&hist[bb.x], 1u);
    atomicAdd(&hist[bb.y], 1u);
  }
  __syncthreads();
  if (tid < 256) suf[tid] = hist[tid];
  __syncthreads();
  for (int off = 1; off < 256; off <<= 1) {
    u32 v = 0;
    if (tid < 256 && tid + off < 256) v = suf[tid + off];
    __syncthreads();
    if (tid < 256) suf[tid] += v;
    __syncthreads();
  }
  if (tid < 256) {
    u32 nxt = (tid < 255) ? suf[tid + 1] : 0u;
    if (suf[tid] >= (u32)KSEL && nxt < (u32)KSEL) shBs = tid;
  }
  __syncthreads();
  int Bs = shBs;
  int lane = tid & 63;
  // pass 2: L2/L3-hot f32 read; bin recomputed from identical stored s
  for (int i = tid; i < AA / 2; i += 512) {
    float2 v = src[i];
    {
      bool p = min(255, (int)(v.x * 256.0f)) >= Bs;
      u64 m = __ballot(p);
      if (p) {
        int leader = (int)(__ffsll((long long)m) - 1);
        int base = 0;
        if (lane == leader) base = atomicAdd(&ctr, (int)__popcll(m));
        base = __shfl(base, leader);
        int pos = base + (int)__popcll(m & ((1ull << lane) - 1ull));
        if (pos < 512)
          cand[pos] = ((u64)__float_as_uint(v.x) << 32) | (u32)(~(u32)(2 * i));
      }
    }
    {
      bool p = min(255, (int)(v.y * 256.0f)) >= Bs;
      u64 m = __ballot(p);
      if (p) {
        int leader = (int)(__ffsll((long long)m) - 1);
        int base = 0;
        if (lane == leader) base = atomicAdd(&ctr, (int)__popcll(m));
        base = __shfl(base, leader);
        int pos = base + (int)__popcll(m & ((1ull << lane) - 1ull));
        if (pos < 512)
          cand[pos] = ((u64)__float_as_uint(v.y) << 32) | (u32)(~(u32)(2 * i + 1));
      }
    }
  }
  __syncthreads();
  int n = ctr < 512 ? ctr : 512;
  for (int i = n + tid; i < 512; i += 512) cand[i] = 0;  // pad sorts low
  __syncthreads();
  // bitonic sort 512 ascending, 1 element per thread
  for (int k = 2; k <= 512; k <<= 1) {
    for (int j = k >> 1; j > 0; j >>= 1) {
      int l = tid ^ j;
      if (l > tid) {
        u64 x = cand[tid], y = cand[l];
        bool asc = ((tid & k) == 0);
        if ((x > y) == asc) { cand[tid] = y; cand[l] = x; }
      }
      __syncthreads();
    }
  }
  if (tid < KSEL) {
    u64 kk = cand[511 - tid];
    tks[(size_t)row * KSEL + tid] = __uint_as_float((u32)(kk >> 32));
    tki[(size_t)row * KSEL + tid] = (int)(~(u32)kk);
  }
}

// ---------------- helpers ----------------
__device__ inline float rdlane(float x, int l) {
  return __int_as_float(__builtin_amdgcn_readlane(__float_as_int(x), l));
}

__device__ inline float4 decode1(const float* __restrict__ enc,
                                 const float* __restrict__ anch, int b, int ai) {
  float4 e  = ((const float4*)enc)[(size_t)b * AA + ai];
  float4 an = ((const float4*)anch)[ai];
  float ty = e.x / 10.0f, tx = e.y / 10.0f, th = e.z / 5.0f, tw = e.w / 5.0f;
  float yc = ty * an.z + an.x;
  float xc = tx * an.w + an.y;
  float h  = expf(th) * an.z;
  float w  = expf(tw) * an.w;
  float4 o;
  o.x = yc - h * 0.5f; o.y = xc - w * 0.5f; o.z = yc + h * 0.5f; o.w = xc + w * 0.5f;
  return o;
}

// ---------------- NMS v4 (R12-verbatim): sorted-scan, exact IoU test -------
__global__ void __launch_bounds__(256) k_nms(const float* __restrict__ enc,
    const float* __restrict__ anch,
    const float* __restrict__ tks, const int* __restrict__ tki,
    float* __restrict__ flat_s, float* __restrict__ flat_b) {
  int wid = threadIdx.x >> 6, lane = threadIdx.x & 63;
  int row = blockIdx.x * 4 + wid;
  int b = row / NCLS, c = row % NCLS;
  const float* trow = tks + (size_t)row * KSEL;
  const int*   irow = tki + (size_t)row * KSEL;
  float s0 = trow[lane], s1 = trow[64 + lane], s2 = trow[128 + lane], s3 = trow[192 + lane];
  int   i0 = irow[lane], i1 = irow[64 + lane], i2 = irow[128 + lane], i3 = irow[192 + lane];
  float4 B0 = decode1(enc, anch, b, i0);
  float4 B1 = decode1(enc, anch, b, i1);
  float4 B2 = decode1(enc, anch, b, i2);
  float4 B3 = decode1(enc, anch, b, i3);
  float a0 = (B0.z - B0.x) * (B0.w - B0.y);
  float a1 = (B1.z - B1.x) * (B1.w - B1.y);
  float a2 = (B2.z - B2.x) * (B2.w - B2.y);
  float a3 = (B3.z - B3.x) * (B3.w - B3.y);
  u64 m0 = __ballot(s0 > 0.0f);
  u64 m1 = __ballot(s1 > 0.0f);
  u64 m2 = __ballot(s2 > 0.0f);
  u64 m3 = __ballot(s3 > 0.0f);
  // exact threshold midpoint: RN(q) >= 0.6f  <=>  q >= M
  const float cP = __uint_as_float(0x3F199999u);   // pred(0.6f)
  const double M = 0.5 * ((double)cP + (double)0.6f);
  float ss0 = 0.0f, ss1 = 0.0f;
  float4 ob0; ob0.x = ob0.y = ob0.z = ob0.w = 0.0f;
  float4 ob1 = ob0;
  size_t fo = (size_t)b * NFLAT + (size_t)c * MAXDET;
  for (int d = 0; d < MAXDET; d++) {
    int kw; u64 w;
    if      (m0) { kw = 0; w = m0; }
    else if (m1) { kw = 1; w = m1; }
    else if (m2) { kw = 2; w = m2; }
    else if (m3) { kw = 3; w = m3; }
    else break;
    int lw = (int)__builtin_ctzll(w);
    float sw_, wx_, wy_, wz_, ww_;
    if (kw == 0) {
      sw_ = rdlane(s0, lw);
      wx_ = rdlane(B0.x, lw); wy_ = rdlane(B0.y, lw);
      wz_ = rdlane(B0.z, lw); ww_ = rdlane(B0.w, lw);
    } else if (kw == 1) {
      sw_ = rdlane(s1, lw);
      wx_ = rdlane(B1.x, lw); wy_ = rdlane(B1.y, lw);
      wz_ = rdlane(B1.z, lw); ww_ = rdlane(B1.w, lw);
    } else if (kw == 2) {
      sw_ = rdlane(s2, lw);
      wx_ = rdlane(B2.x, lw); wy_ = rdlane(B2.y, lw);
      wz_ = rdlane(B2.z, lw); ww_ = rdlane(B2.w, lw);
    } else {
      sw_ = rdlane(s3, lw);
      wx_ = rdlane(B3.x, lw); wy_ = rdlane(B3.y, lw);
      wz_ = rdlane(B3.z, lw); ww_ = rdlane(B3.w, lw);
    }
    // register-buffered output capture (no divergent store)
    bool c0 = (lane == d);
    bool c1 = (lane + 64 == d);
    ss0 = c0 ? sw_ : ss0;
    ob0.x = c0 ? wx_ : ob0.x; ob0.y = c0 ? wy_ : ob0.y;
    ob0.z = c0 ? wz_ : ob0.z; ob0.w = c0 ? ww_ : ob0.w;
    ss1 = c1 ? sw_ : ss1;
    ob1.x = c1 ? wx_ : ob1.x; ob1.y = c1 ? wy_ : ob1.y;
    ob1.z = c1 ? wz_ : ob1.z; ob1.w = c1 ? ww_ : ob1.w;
    float ia = (wz_ - wx_) * (ww_ - wy_);
    float in0, in1, in2, in3, un0, un1, un2, un3;
#define PAIR(BX, AK, INK, UNK) { \
      float ty = fmaxf(wx_, BX.x), tx = fmaxf(wy_, BX.y); \
      float by = fminf(wz_, BX.z), bw = fminf(ww_, BX.w); \
      float hh = fmaxf(by - ty, 0.0f), wvv = fmaxf(bw - tx, 0.0f); \
      INK = hh * wvv; \
      UNK = fmaxf(ia + AK - INK, 1e-8f); }
    PAIR(B0, a0, in0, un0)
    PAIR(B1, a1, in1, un1)
    PAIR(B2, a2, in2, un2)
    PAIR(B3, a3, in3, un3)
#undef PAIR
    u64 cm0 = __ballot((double)in0 >= M * (double)un0);
    u64 cm1 = __ballot((double)in1 >= M * (double)un1);
    u64 cm2 = __ballot((double)in2 >= M * (double)un2);
    u64 cm3 = __ballot((double)in3 >= M * (double)un3);
    m0 &= ~cm0; m1 &= ~cm1; m2 &= ~cm2; m3 &= ~cm3;
  }
  flat_s[fo + lane] = ss0;
  ((float4*)flat_b)[fo + lane] = ob0;
  if (lane < MAXDET - 64) {
    flat_s[fo + 64 + lane] = ss1;
    ((float4*)flat_b)[fo + 64 + lane] = ob1;
  }
}

// ---------------- bitonic sorts (block of 256 threads) ----------------
__device__ inline void bitonic_u64_asc(u64* a, int n, int tid) {
  for (int k = 2; k <= n; k <<= 1) {
    for (int j = k >> 1; j > 0; j >>= 1) {
      for (int i = tid; i < n; i += 256) {
        int l = i ^ j;
        if (l > i) {
          u64 x = a[i], y = a[l];
          bool asc = ((i & k) == 0);
          if ((x > y) == asc) { a[i] = y; a[l] = x; }
        }
      }
      __syncthreads();
    }
  }
}
__device__ inline void bitonic_u32_asc(u32* a, int n, int tid) {
  for (int k = 2; k <= n; k <<= 1) {
    for (int j = k >> 1; j > 0; j >>= 1) {
      for (int i = tid; i < n; i += 256) {
        int l = i ^ j;
        if (l > i) {
          u32 x = a[i], y = a[l];
          bool asc = ((i & k) == 0);
          if ((x > y) == asc) { a[i] = y; a[l] = x; }
        }
      }
      __syncthreads();
    }
  }
}

// ---------------- exact radix select (rank kwant, descending) ----------------
template<typename F>
__device__ inline void radix_select(F getv, int n, int kwant,
    u32* hist, u32* suf, int* sh2, int tid,
    u32& V_out, int& GT_out, int& r_out) {
  int r = kwant; u32 V = 0; int GT = 0;
  for (int lvl = 0; lvl < 3; lvl++) {
    int shift = (lvl == 0) ? 19 : ((lvl == 1) ? 8 : 0);
    int nbins = (lvl == 2) ? 256 : 2048;
    for (int i = tid; i < nbins; i += 256) hist[i] = 0;
    __syncthreads();
    for (int idx = tid; idx < n; idx += 256) {
      u32 u = __float_as_uint(getv(idx));
      bool ok = (lvl == 0) || (lvl == 1 ? ((u >> 19) == (V >> 19))
                                        : ((u >> 8)  == (V >> 8)));
      u64 zm = __ballot(ok && u == 0u);
      if (ok) {
        if (u == 0u) {
          if ((int)(threadIdx.x & 63) == (int)(__ffsll((long long)zm) - 1))
            atomicAdd(&hist[0], (u32)__popcll(zm));
        } else {
          atomicAdd(&hist[(u >> shift) & (u32)(nbins - 1)], 1u);
        }
      }
    }
    __syncthreads();
    int G = nbins >> 8;
    u32 ps = 0;
    for (int g = 0; g < G; g++) ps += hist[tid * G + g];
    suf[tid] = ps;
    __syncthreads();
    for (int off = 1; off < 256; off <<= 1) {
      u32 v = (tid + off < 256) ? suf[tid + off] : 0u;
      __syncthreads();
      suf[tid] += v;
      __syncthreads();
    }
    u32 sufnext = (tid < 255) ? suf[tid + 1] : 0u;
    if (suf[tid] >= (u32)r && sufnext < (u32)r) {
      u32 cum = sufnext; int kb = tid * G;
      for (int bin = tid * G + G - 1; bin >= tid * G; bin--) {
        cum += hist[bin];
        if (cum >= (u32)r) { kb = bin; break; }
      }
      sh2[0] = kb;
      sh2[1] = (int)(cum - hist[kb]);
    }
    __syncthreads();
    int kb = sh2[0], gt = sh2[1];
    r -= gt; GT += gt; V |= ((u32)kb) << shift;
    __syncthreads();
  }
  V_out = V; GT_out = GT; r_out = r;
}

// ---------------- fallback: direct strided top-256 (small ws only) ----------
__global__ void __launch_bounds__(256) k_topk_direct(const float* __restrict__ src,
    float* __restrict__ tks, int* __restrict__ tki) {
  __shared__ u32 hist[2048];
  __shared__ u32 suf[256];
  __shared__ int sh2[2];
  __shared__ u64 sel[KSEL];
  __shared__ u32 tie[512];
  __shared__ int cgt, ctie;
  int row = blockIdx.x, tid = threadIdx.x;
  int b = row / NCLS, c = row % NCLS;
  const float* base = src + (size_t)b * AA * CCH + (c + 1);
  auto getv = [&](int i) -> float {
    float x = base[(size_t)i * CCH]; return 1.0f / (1.0f + expf(-x));
  };
  u32 V; int GT, r;
  radix_select(getv, AA, KSEL, hist, suf, sh2, tid, V, GT, r);
  if (tid == 0) { cgt = 0; ctie = 0; }
  __syncthreads();
  for (int i = tid; i < AA; i += 256) {
    u32 u = __float_as_uint(getv(i));
    if (u > V) {
      int p = atomicAdd(&cgt, 1);
      sel[p] = ((u64)u << 32) | (u32)(~(u32)i);
    } else if (u == V) {
      int p = atomicAdd(&ctie, 1);
      if (p < 512) tie[p] = (u32)i;
    }
  }
  __syncthreads();
  int nt = ctie < 512 ? ctie : 512;
  for (int i = tid + nt; i < 512; i += 256) tie[i] = 0xFFFFFFFFu;
  __syncthreads();
  bitonic_u32_asc(tie, 512, tid);
  for (int i = tid; i < r; i += 256)
    sel[GT + i] = ((u64)V << 32) | (u32)(~tie[i]);
  __syncthreads();
  bitonic_u64_asc(sel, KSEL, tid);
  for (int j = tid; j < KSEL; j += 256) {
    u64 kk = sel[KSEL - 1 - j];
    tks[(size_t)row * KSEL + j] = __uint_as_float((u32)(kk >> 32));
    tki[(size_t)row * KSEL + j] = (int)(~(u32)kk);
  }
}

// ---------------- final per-batch top-100: arith-bin + single sort ---------
__global__ void __launch_bounds__(512) k_final(const float* __restrict__ flat_s,
    const float* __restrict__ flat_b, float* __restrict__ out) {
  __shared__ u32 hist[256];
  __shared__ u32 suf[256];
  __shared__ u64 cand[512];
  __shared__ int shBs, ctr;
  int b = blockIdx.x, tid = threadIdx.x;
  int lane = tid & 63;
  const float2* src = (const float2*)(flat_s + (size_t)b * NFLAT);  // 9000 even
  if (tid < 256) hist[tid] = 0;
  if (tid == 0) ctr = 0;
  __syncthreads();
  for (int i = tid; i < NFLAT / 2; i += 512) {
    float2 v = src[i];
    atomicAdd(&hist[min(255, (int)(v.x * 256.0f))], 1u);
    atomicAdd(&hist[min(255, (int)(v.y * 256.0f))], 1u);
  }
  __syncthreads();
  if (tid < 256) suf[tid] = hist[tid];
  __syncthreads();
  for (int off = 1; off < 256; off <<= 1) {
    u32 v = 0;
    if (tid < 256 && tid + off < 256) v = suf[tid + off];
    __syncthreads();
    if (tid < 256) suf[tid] += v;
    __syncthreads();
  }
  if (tid < 256) {
    u32 nxt = (tid < 255) ? suf[tid + 1] : 0u;
    if (suf[tid] >= (u32)MAXDET && nxt < (u32)MAXDET) shBs = tid;
  }
  __syncthreads();
  int Bs = shBs;
  for (int i = tid; i < NFLAT / 2; i += 512) {
    float2 v = src[i];
    {
      bool p = min(255, (int)(v.x * 256.0f)) >= Bs;
      u64 m = __ballot(p);
      if (p) {
        int leader = (int)(__ffsll((long long)m) - 1);
        int base = 0;
        if (lane == leader) base = atomicAdd(&ctr, (int)__popcll(m));
        base = __shfl(base, leader);
        int pos = base + (int)__popcll(m & ((1ull << lane) - 1ull));
        if (pos < 512)
          cand[pos] = ((u64)__float_as_uint(v.x) << 32) | (u32)(~(u32)(2 * i));
      }
    }
    {
      bool p = min(255, (int)(v.y * 256.0f)) >= Bs;
      u64 m = __ballot(p);
      if (p) {
        int leader = (int)(__ffsll((long long)m) - 1);
        int base = 0;
        if (lane == leader) base = atomicAdd(&ctr, (int)__popcll(m));
        base = __shfl(base, leader);
        int pos = base + (int)__popcll(m & ((1ull << lane) - 1ull));
        if (pos < 512)
          cand[pos] = ((u64)__float_as_uint(v.y) << 32) | (u32)(~(u32)(2 * i + 1));
      }
    }
  }
  __syncthreads();
  int n = ctr < 512 ? ctr : 512;
  for (int i = n + tid; i < 512; i += 512) cand[i] = 0;  // pad sorts low
  __syncthreads();
  for (int k = 2; k <= 512; k <<= 1) {
    for (int j = k >> 1; j > 0; j >>= 1) {
      int l = tid ^ j;
      if (l > tid) {
        u64 x = cand[tid], y = cand[l];
        bool asc = ((tid & k) == 0);
        if ((x > y) == asc) { cand[tid] = y; cand[l] = x; }
      }
      __syncthreads();
    }
  }
  if (tid < MAXDET) {
    u64 kk = cand[511 - tid];
    u32 u  = (u32)(kk >> 32);
    int fi = (int)(~(u32)kk);
    float4 bb = ((const float4*)flat_b)[(size_t)b * NFLAT + fi];
    float* o = out + ((size_t)b * MAXDET + tid) * 6;
    o[0] = bb.x; o[1] = bb.y; o[2] = bb.z; o[3] = bb.w;
    o[4] = (float)(fi / 100 + 1);
    o[5] = __uint_as_float(u);
  }
}

// ---------------- launch ----------------
extern "C" void kernel_launch(void* const* d_in, const int* in_sizes, int n_in,
                              void* d_out, int out_size, void* d_ws, size_t ws_size,
                              hipStream_t stream) {
  const float* enc    = (const float*)d_in[0];
  const float* logits = (const float*)d_in[1];
  const float* anch   = (const float*)d_in[2];
  float* out = (float*)d_out;
  char* ws = (char*)d_ws;

  size_t off = 0;
  auto alloc = [&](size_t bytes) {
    size_t o = off;
    off += (bytes + 255) & ~(size_t)255;
    return o;
  };
  size_t o_tks  = alloc((size_t)NROWS * KSEL * 4);
  size_t o_tki  = alloc((size_t)NROWS * KSEL * 4);
  size_t o_fls  = alloc((size_t)BB * NFLAT * 4);
  size_t o_flb  = alloc((size_t)BB * NFLAT * 16);
  size_t need_base = off;
  size_t o_sc = off;                                   // chunked sc+sbin here
  size_t per_batch_sc   = ((size_t)NCLS * AA * 4 + 255) & ~(size_t)255; // 6.92 MB
  size_t per_batch_sbin = ((size_t)NCLS * AA + 255) & ~(size_t)255;     // 1.73 MB

  int CB = 0;
  for (int cb = BB; cb >= 1; cb >>= 1) {
    if (ws_size >= need_base + (size_t)cb * (per_batch_sc + per_batch_sbin)) {
      CB = cb; break;
    }
  }

  float* tks = (float*)(ws + o_tks);
  int*   tki = (int*)  (ws + o_tki);
  float* fls = (float*)(ws + o_fls);
  float* flb = (float*)(ws + o_flb);
  float* scp = (float*)(ws + o_sc);
  u8*    sbp = (u8*)   (ws + o_sc + (size_t)CB * per_batch_sc);

  if (CB > 0) {
    for (int b0 = 0; b0 < BB; b0 += CB) {
      hipLaunchKernelGGL(k_sigT, dim3((AA + ATILE - 1) / ATILE, CB), dim3(256), 0,
                         stream, logits, scp, sbp, b0);
      hipLaunchKernelGGL(k_row, dim3(NCLS * CB), dim3(512), 0, stream,
                         scp, sbp, tks, tki, b0 * NCLS);
    }
  } else {
    hipLaunchKernelGGL(k_topk_direct, dim3(NROWS), dim3(256), 0, stream,
                       logits, tks, tki);
  }
  hipLaunchKernelGGL(k_nms, dim3(NROWS / 4), dim3(256), 0, stream,
                     enc, anch, tks, tki, fls, flb);
  hipLaunchKernelGGL(k_final, dim3(BB), dim3(512), 0, stream,
                     fls, flb, out);
}